// Round 1
// baseline (701.990 us; speedup 1.0000x reference)
//
#include <hip/hip_runtime.h>
#include <math.h>

namespace {
constexpr int Bn = 4, Cn = 64, Hn = 240, Wn = 320;
constexpr int Npix = Bn * Hn * Wn;          // 307200
constexpr float EPS = 1e-5f;
constexpr float SLOPE = 0.2f;
}

// Fused DKN: 1x1 conv+BN+LReLU (depth->df), [df|feature] 3x3 convs -> 9 weight
// + 18 offset channels, BN+sigmoid+zero-mean, deformable 3x3 bilinear sample
// of 15x15 depth patch, residual add.
// 1 thread = 1 output pixel. fp32 everywhere (round 1: correctness baseline).
__global__ __launch_bounds__(256) void dkn_fused_f32(
    const float* __restrict__ depth,    // (B,1,H,W)
    const float* __restrict__ feature,  // (B,64,H,W)
    const float* __restrict__ w1,       // (64)
    const float* __restrict__ g1, const float* __restrict__ b1,
    const float* __restrict__ m1, const float* __restrict__ v1,
    const float* __restrict__ ww,       // (9,128,3,3)
    const float* __restrict__ gw, const float* __restrict__ bw,
    const float* __restrict__ mw, const float* __restrict__ vw,
    const float* __restrict__ wo,       // (18,128,3,3)
    const float* __restrict__ go, const float* __restrict__ bo,
    const float* __restrict__ mo, const float* __restrict__ vo,
    float* __restrict__ out)            // (B,1,H,W)
{
    const int n = blockIdx.x * blockDim.x + threadIdx.x;
    if (n >= Npix) return;
    const int w = n % Wn;
    const int h = (n / Wn) % Hn;
    const int b = n / (Wn * Hn);

    const float* __restrict__ dimg = depth + (size_t)b * Hn * Wn;
    const float* __restrict__ fimg = feature + (size_t)b * Cn * Hn * Wn;

    // 3x3 neighborhood of depth (clamped load + validity mask; conv pad
    // zeros apply to cat AFTER df, so padded taps must contribute 0).
    float d9[9];
    float msk[9];
    int   off9[9];   // clamped (y*W+x) offsets, reused for feature loads
    #pragma unroll
    for (int ky = 0; ky < 3; ++ky) {
        #pragma unroll
        for (int kx = 0; kx < 3; ++kx) {
            const int t = ky * 3 + kx;
            const int y = h + ky - 1, x = w + kx - 1;
            const bool ok = ((unsigned)y < (unsigned)Hn) && ((unsigned)x < (unsigned)Wn);
            const int ycl = min(max(y, 0), Hn - 1);
            const int xcl = min(max(x, 0), Wn - 1);
            off9[t] = ycl * Wn + xcl;
            d9[t]  = dimg[off9[t]];
            msk[t] = ok ? 1.0f : 0.0f;
        }
    }

    float accW[9], accO[18];
    #pragma unroll
    for (int o = 0; o < 9; ++o)  accW[o] = 0.0f;
    #pragma unroll
    for (int o = 0; o < 18; ++o) accO[o] = 0.0f;

    // ---- df half: cat channels 0..63 (depth * w1 -> BN -> LReLU) ----
    for (int c = 0; c < Cn; ++c) {
        const float inv = g1[c] * rsqrtf(v1[c] + EPS);
        const float A   = w1[c] * inv;
        const float Bc  = b1[c] - m1[c] * inv;
        float v9[9];
        #pragma unroll
        for (int t = 0; t < 9; ++t) {
            const float x = fmaf(A, d9[t], Bc);
            v9[t] = msk[t] * fmaxf(x, SLOPE * x);   // lrelu, slope<1
        }
        const float* __restrict__ wwc = ww + c * 9;   // + o*1152 + t
        const float* __restrict__ woc = wo + c * 9;
        #pragma unroll
        for (int o = 0; o < 9; ++o) {
            #pragma unroll
            for (int t = 0; t < 9; ++t)
                accW[o] = fmaf(wwc[o * 1152 + t], v9[t], accW[o]);
        }
        #pragma unroll
        for (int o = 0; o < 18; ++o) {
            #pragma unroll
            for (int t = 0; t < 9; ++t)
                accO[o] = fmaf(woc[o * 1152 + t], v9[t], accO[o]);
        }
    }

    // ---- feature half: cat channels 64..127 ----
    for (int c = 0; c < Cn; ++c) {
        const float* __restrict__ fc = fimg + (size_t)c * Hn * Wn;
        float v9[9];
        #pragma unroll
        for (int t = 0; t < 9; ++t)
            v9[t] = msk[t] * fc[off9[t]];
        const float* __restrict__ wwc = ww + (64 + c) * 9;
        const float* __restrict__ woc = wo + (64 + c) * 9;
        #pragma unroll
        for (int o = 0; o < 9; ++o) {
            #pragma unroll
            for (int t = 0; t < 9; ++t)
                accW[o] = fmaf(wwc[o * 1152 + t], v9[t], accW[o]);
        }
        #pragma unroll
        for (int o = 0; o < 18; ++o) {
            #pragma unroll
            for (int t = 0; t < 9; ++t)
                accO[o] = fmaf(woc[o * 1152 + t], v9[t], accO[o]);
        }
    }

    // ---- BN + sigmoid + zero-mean over 9 taps ----
    float wgt[9];
    float wsum = 0.0f;
    #pragma unroll
    for (int j = 0; j < 9; ++j) {
        const float inv = gw[j] * rsqrtf(vw[j] + EPS);
        const float x = fmaf(accW[j], inv, bw[j] - mw[j] * inv);
        const float s = 1.0f / (1.0f + expf(-x));
        wgt[j] = s;
        wsum += s;
    }
    const float wm = wsum * (1.0f / 9.0f);
    #pragma unroll
    for (int j = 0; j < 9; ++j) wgt[j] -= wm;

    float offv[18];
    #pragma unroll
    for (int j = 0; j < 18; ++j) {
        const float inv = go[j] * rsqrtf(vo[j] + EPS);
        offv[j] = fmaf(accO[j], inv, bo[j] - mo[j] * inv);
    }

    // ---- deformable 3x3 bilinear sampling on the 15x15 depth patch ----
    // patch coord (xi,yi) maps to depth[h + yi - 7, w + xi - 7], zero outside
    // patch range [0,14] and outside the image.
    auto sampleD = [&](float xf, float yf) -> float {
        const bool vld = (xf >= 0.0f) & (xf <= 14.0f) & (yf >= 0.0f) & (yf <= 14.0f);
        const float xc = fminf(fmaxf(xf, 0.0f), 14.0f);
        const float yc = fminf(fmaxf(yf, 0.0f), 14.0f);
        const int xi = (int)xc, yi = (int)yc;
        const int yy = h + yi - 7, xx = w + xi - 7;
        const bool okimg = ((unsigned)yy < (unsigned)Hn) && ((unsigned)xx < (unsigned)Wn);
        return (vld && okimg) ? dimg[yy * Wn + xx] : 0.0f;
    };

    float res = 0.0f;
    #pragma unroll
    for (int i = 0; i < 3; ++i) {
        #pragma unroll
        for (int j = 0; j < 3; ++j) {
            const int t = i * 3 + j;
            const float ox = offv[2 * t + 0];
            const float oy = offv[2 * t + 1];
            const float ix = (7.0f + (float)i + ox) * (14.0f / 15.0f);
            const float iy = (7.0f + (float)j + oy) * (14.0f / 15.0f);
            const float x0 = floorf(ix), y0 = floorf(iy);
            const float wx1 = ix - x0, wy1 = iy - y0;
            const float wx0 = 1.0f - wx1, wy0 = 1.0f - wy1;
            const float s =
                  sampleD(x0,        y0       ) * wx0 * wy0
                + sampleD(x0 + 1.0f, y0       ) * wx1 * wy0
                + sampleD(x0,        y0 + 1.0f) * wx0 * wy1
                + sampleD(x0 + 1.0f, y0 + 1.0f) * wx1 * wy1;
            res = fmaf(s, wgt[t], res);
        }
    }

    out[n] = res + dimg[h * Wn + w];
}

extern "C" void kernel_launch(void* const* d_in, const int* in_sizes, int n_in,
                              void* d_out, int out_size, void* d_ws, size_t ws_size,
                              hipStream_t stream) {
    const float* depth   = (const float*)d_in[0];
    const float* feature = (const float*)d_in[1];
    const float* w1 = (const float*)d_in[2];
    const float* g1 = (const float*)d_in[3];
    const float* b1 = (const float*)d_in[4];
    const float* m1 = (const float*)d_in[5];
    const float* v1 = (const float*)d_in[6];
    const float* ww = (const float*)d_in[7];
    const float* gw = (const float*)d_in[8];
    const float* bw = (const float*)d_in[9];
    const float* mw = (const float*)d_in[10];
    const float* vw = (const float*)d_in[11];
    const float* wo = (const float*)d_in[12];
    const float* go = (const float*)d_in[13];
    const float* bo = (const float*)d_in[14];
    const float* mo = (const float*)d_in[15];
    const float* vo = (const float*)d_in[16];
    float* out = (float*)d_out;

    const int threads = 256;
    const int blocks = (Npix + threads - 1) / threads;  // 1200
    hipLaunchKernelGGL(dkn_fused_f32, dim3(blocks), dim3(threads), 0, stream,
                       depth, feature, w1, g1, b1, m1, v1,
                       ww, gw, bw, mw, vw, wo, go, bo, mo, vo, out);
}

// Round 2
// 164.011 us; speedup vs baseline: 4.2801x; 4.2801x over previous
//
#include <hip/hip_runtime.h>
#include <math.h>

namespace {
constexpr int Bn = 4, Cn = 64, Hn = 240, Wn = 320;
constexpr int Npix = Bn * Hn * Wn;
constexpr int HP = Hn + 2, WP = Wn + 2;      // padded 242 x 322
constexpr float EPS = 1e-5f;
constexpr float SLOPE = 0.2f;
constexpr int TM = 16, TN = 32;              // output tile: 16 rows x 32 cols
constexpr int HR = TM + 2, HC = TN + 2;      // halo tile: 18 x 34
constexpr size_t CATT_ELEMS = (size_t)Bn * HP * WP * 128;   // bf16 elems
constexpr size_t CATT_OFF = 131072;                          // bytes (Bmat first)
constexpr size_t WS_NEED = CATT_OFF + CATT_ELEMS * 2;
}

typedef __attribute__((ext_vector_type(8))) short bf16x8;
typedef __attribute__((ext_vector_type(4))) float f32x4;

__device__ inline unsigned short f2bf(float f) {
    unsigned u = __builtin_bit_cast(unsigned, f);
    return (unsigned short)((u + 0x7fffu + ((u >> 16) & 1u)) >> 16);
}

// ---------------- pre-pass 1: cat = [df | feature] -> padded bf16, swizzled ----
// catT[b][ph][pc][128ch] bf16; within each pixel's 256B block, 16B granule g
// (channels 8g..8g+7) stored at slot g ^ (pc & 7). Border pixels = 0.
__global__ __launch_bounds__(256) void prep_cat(
    const float* __restrict__ depth, const float* __restrict__ feature,
    const float* __restrict__ w1, const float* __restrict__ g1,
    const float* __restrict__ b1, const float* __restrict__ m1,
    const float* __restrict__ v1,
    unsigned short* __restrict__ catT)
{
    const int slot = blockIdx.x * 256 + threadIdx.x;   // (pc, g)
    if (slot >= WP * 16) return;
    const int pc = slot >> 4, g = slot & 15;
    const int ph = blockIdx.y, b = blockIdx.z;

    unsigned short vals[8];
    if (ph == 0 || ph == HP - 1 || pc == 0 || pc == WP - 1) {
        #pragma unroll
        for (int j = 0; j < 8; ++j) vals[j] = 0;
    } else {
        const int y = ph - 1, x = pc - 1;
        if (g < 8) {   // df channels 8g..8g+7
            const float d = depth[((size_t)b * Hn + y) * Wn + x];
            #pragma unroll
            for (int j = 0; j < 8; ++j) {
                const int c = g * 8 + j;
                const float inv = g1[c] * rsqrtf(v1[c] + EPS);
                const float u = fmaf(w1[c] * inv, d, b1[c] - m1[c] * inv);
                vals[j] = f2bf(fmaxf(u, SLOPE * u));
            }
        } else {       // feature channels (g-8)*8 ..
            const int c0 = (g - 8) * 8;
            #pragma unroll
            for (int j = 0; j < 8; ++j)
                vals[j] = f2bf(feature[(((size_t)b * Cn + c0 + j) * Hn + y) * Wn + x]);
        }
    }
    unsigned short* dst = catT + (((size_t)b * HP + ph) * WP + pc) * 128
                               + (size_t)(g ^ (pc & 7)) * 8;
    uint4 v;
    v.x = (unsigned)vals[0] | ((unsigned)vals[1] << 16);
    v.y = (unsigned)vals[2] | ((unsigned)vals[3] << 16);
    v.z = (unsigned)vals[4] | ((unsigned)vals[5] << 16);
    v.w = (unsigned)vals[6] | ((unsigned)vals[7] << 16);
    *(uint4*)dst = v;
}

// ---------------- pre-pass 2: weights -> bf16 B[32][1152], k = t*128 + c ----
__global__ __launch_bounds__(256) void prep_B(
    const float* __restrict__ ww, const float* __restrict__ wo,
    unsigned short* __restrict__ Bmat)
{
    const int k = blockIdx.x * 256 + threadIdx.x;
    if (k >= 1152) return;
    const int col = blockIdx.y;           // 0..31 (27..31 zero-pad)
    const int t = k >> 7, c = k & 127;
    float v = 0.0f;
    if (col < 9)       v = ww[((size_t)col * 128 + c) * 9 + t];
    else if (col < 27) v = wo[((size_t)(col - 9) * 128 + c) * 9 + t];
    Bmat[(size_t)col * 1152 + k] = f2bf(v);
}

// ---------------- main: MFMA implicit GEMM + fused epilogue ----------------
__global__ __launch_bounds__(512, 1) void dkn_main(
    const unsigned short* __restrict__ catT,
    const unsigned short* __restrict__ Bmat,
    const float* __restrict__ depth,
    const float* __restrict__ gw, const float* __restrict__ bw,
    const float* __restrict__ mw, const float* __restrict__ vw,
    const float* __restrict__ go, const float* __restrict__ bo,
    const float* __restrict__ mo, const float* __restrict__ vo,
    float* __restrict__ out)
{
    __shared__ __align__(16) char lds[HR * HC * 256];   // 156672 B

    const int tid = threadIdx.x;
    const int b = blockIdx.z;
    const int h0 = blockIdx.y * TM;     // image row origin
    const int w0 = blockIdx.x * TN;     // image col origin

    // ---- stage A-tile: padded rows h0..h0+17, padded cols w0..w0+33 ----
    for (int r = 0; r < HR; ++r) {
        const unsigned short* src =
            catT + (((size_t)b * HP + h0 + r) * WP + w0) * 128;
        for (int s = tid; s < HC * 16; s += 512) {
            uint4 v = *(const uint4*)(src + s * 8);
            *(uint4*)(lds + (size_t)((r * HC + (s >> 4)) * 16 + (s & 15)) * 16) = v;
        }
    }
    __syncthreads();

    const int lane = tid & 63, wv = tid >> 6;
    const int l15 = lane & 15, hi = lane >> 4;

    f32x4 acc[4][2] = {};

    int abase[4];
    #pragma unroll
    for (int m = 0; m < 4; ++m) {
        const int oy = 2 * wv + (m >> 1), xh = m & 1;
        abase[m] = (oy * HC + xh * 16 + l15) * 256;
    }
    int key[3];
    #pragma unroll
    for (int d = 0; d < 3; ++d) key[d] = (l15 + d) & 7;

    const unsigned short* bp0 = Bmat + ((size_t)l15 * 1152 + hi * 8);
    const unsigned short* bp1 = Bmat + ((size_t)(l15 + 16) * 1152 + hi * 8);

    bf16x8 bn0 = *(const bf16x8*)bp0;
    bf16x8 bn1 = *(const bf16x8*)bp1;

    #pragma unroll
    for (int kc = 0; kc < 36; ++kc) {
        const bf16x8 bc0 = bn0, bc1 = bn1;
        if (kc < 35) {
            bn0 = *(const bf16x8*)(bp0 + (kc + 1) * 32);
            bn1 = *(const bf16x8*)(bp1 + (kc + 1) * 32);
        }
        const int t = kc >> 2, q = kc & 3;
        const int dy = t / 3, dx = t % 3;
        const int gq = ((q * 4 + hi) ^ key[dx]) << 4;   // swizzled granule byte off
        const int cofs = dy * (HC * 256) + dx * 256;
        #pragma unroll
        for (int m = 0; m < 4; ++m) {
            bf16x8 a = *(const bf16x8*)(lds + abase[m] + cofs + gq);
            acc[m][0] = __builtin_amdgcn_mfma_f32_16x16x32_bf16(a, bc0, acc[m][0], 0, 0, 0);
            acc[m][1] = __builtin_amdgcn_mfma_f32_16x16x32_bf16(a, bc1, acc[m][1], 0, 0, 0);
        }
    }

    // ---- transpose acc -> LDS [512 px][33 f32] ----
    __syncthreads();
    float* ldsE = (float*)lds;
    #pragma unroll
    for (int m = 0; m < 4; ++m) {
        const int oy = 2 * wv + (m >> 1), xh = m & 1;
        #pragma unroll
        for (int n = 0; n < 2; ++n) {
            #pragma unroll
            for (int r = 0; r < 4; ++r) {
                const int ox = xh * 16 + hi * 4 + r;
                ldsE[(oy * TN + ox) * 33 + n * 16 + l15] = acc[m][n][r];
            }
        }
    }
    __syncthreads();

    // ---- per-pixel epilogue (1 thread = 1 pixel) ----
    {
        const int oyl = tid >> 5, oxl = tid & 31;
        const int h = h0 + oyl, w = w0 + oxl;
        const float* __restrict__ dimg = depth + (size_t)b * Hn * Wn;
        const float* row = &ldsE[(size_t)tid * 33];

        float wgt[9];
        float wsum = 0.0f;
        #pragma unroll
        for (int j = 0; j < 9; ++j) {
            const float inv = gw[j] * rsqrtf(vw[j] + EPS);
            const float x = fmaf(row[j], inv, bw[j] - mw[j] * inv);
            const float s = 1.0f / (1.0f + expf(-x));
            wgt[j] = s;
            wsum += s;
        }
        const float wm = wsum * (1.0f / 9.0f);
        #pragma unroll
        for (int j = 0; j < 9; ++j) wgt[j] -= wm;

        float offv[18];
        #pragma unroll
        for (int j = 0; j < 18; ++j) {
            const float inv = go[j] * rsqrtf(vo[j] + EPS);
            offv[j] = fmaf(row[9 + j], inv, bo[j] - mo[j] * inv);
        }

        auto sampleD = [&](float xf, float yf) -> float {
            const bool vld = (xf >= 0.0f) & (xf <= 14.0f) & (yf >= 0.0f) & (yf <= 14.0f);
            const float xc = fminf(fmaxf(xf, 0.0f), 14.0f);
            const float yc = fminf(fmaxf(yf, 0.0f), 14.0f);
            const int xi = (int)xc, yi = (int)yc;
            const int yy = h + yi - 7, xx = w + xi - 7;
            const bool okimg = ((unsigned)yy < (unsigned)Hn) && ((unsigned)xx < (unsigned)Wn);
            return (vld && okimg) ? dimg[yy * Wn + xx] : 0.0f;
        };

        float res = 0.0f;
        #pragma unroll
        for (int i = 0; i < 3; ++i) {
            #pragma unroll
            for (int j = 0; j < 3; ++j) {
                const int t = i * 3 + j;
                const float ox = offv[2 * t + 0];
                const float oy = offv[2 * t + 1];
                const float ix = (7.0f + (float)i + ox) * (14.0f / 15.0f);
                const float iy = (7.0f + (float)j + oy) * (14.0f / 15.0f);
                const float x0 = floorf(ix), y0 = floorf(iy);
                const float wx1 = ix - x0, wy1 = iy - y0;
                const float wx0 = 1.0f - wx1, wy0 = 1.0f - wy1;
                const float s =
                      sampleD(x0,        y0       ) * wx0 * wy0
                    + sampleD(x0 + 1.0f, y0       ) * wx1 * wy0
                    + sampleD(x0,        y0 + 1.0f) * wx0 * wy1
                    + sampleD(x0 + 1.0f, y0 + 1.0f) * wx1 * wy1;
                res = fmaf(s, wgt[t], res);
            }
        }
        out[((size_t)b * Hn + h) * Wn + w] = res + dimg[h * Wn + w];
    }
}

// ---------------- round-1 fallback (fp32, fused, proven) ----------------
__global__ __launch_bounds__(256) void dkn_fused_f32(
    const float* __restrict__ depth, const float* __restrict__ feature,
    const float* __restrict__ w1, const float* __restrict__ g1,
    const float* __restrict__ b1, const float* __restrict__ m1,
    const float* __restrict__ v1, const float* __restrict__ ww,
    const float* __restrict__ gw, const float* __restrict__ bw,
    const float* __restrict__ mw, const float* __restrict__ vw,
    const float* __restrict__ wo, const float* __restrict__ go,
    const float* __restrict__ bo, const float* __restrict__ mo,
    const float* __restrict__ vo, float* __restrict__ out)
{
    const int n = blockIdx.x * blockDim.x + threadIdx.x;
    if (n >= Npix) return;
    const int w = n % Wn;
    const int h = (n / Wn) % Hn;
    const int b = n / (Wn * Hn);
    const float* __restrict__ dimg = depth + (size_t)b * Hn * Wn;
    const float* __restrict__ fimg = feature + (size_t)b * Cn * Hn * Wn;
    float d9[9], msk[9]; int off9[9];
    #pragma unroll
    for (int ky = 0; ky < 3; ++ky)
        #pragma unroll
        for (int kx = 0; kx < 3; ++kx) {
            const int t = ky * 3 + kx;
            const int y = h + ky - 1, x = w + kx - 1;
            const bool ok = ((unsigned)y < (unsigned)Hn) && ((unsigned)x < (unsigned)Wn);
            off9[t] = min(max(y, 0), Hn - 1) * Wn + min(max(x, 0), Wn - 1);
            d9[t] = dimg[off9[t]];
            msk[t] = ok ? 1.0f : 0.0f;
        }
    float accW[9], accO[18];
    #pragma unroll
    for (int o = 0; o < 9; ++o) accW[o] = 0.0f;
    #pragma unroll
    for (int o = 0; o < 18; ++o) accO[o] = 0.0f;
    for (int c = 0; c < Cn; ++c) {
        const float inv = g1[c] * rsqrtf(v1[c] + EPS);
        const float A = w1[c] * inv, Bc = b1[c] - m1[c] * inv;
        float v9[9];
        #pragma unroll
        for (int t = 0; t < 9; ++t) {
            const float x = fmaf(A, d9[t], Bc);
            v9[t] = msk[t] * fmaxf(x, SLOPE * x);
        }
        const float* wwc = ww + c * 9;
        const float* woc = wo + c * 9;
        #pragma unroll
        for (int o = 0; o < 9; ++o)
            #pragma unroll
            for (int t = 0; t < 9; ++t) accW[o] = fmaf(wwc[o * 1152 + t], v9[t], accW[o]);
        #pragma unroll
        for (int o = 0; o < 18; ++o)
            #pragma unroll
            for (int t = 0; t < 9; ++t) accO[o] = fmaf(woc[o * 1152 + t], v9[t], accO[o]);
    }
    for (int c = 0; c < Cn; ++c) {
        const float* fc = fimg + (size_t)c * Hn * Wn;
        float v9[9];
        #pragma unroll
        for (int t = 0; t < 9; ++t) v9[t] = msk[t] * fc[off9[t]];
        const float* wwc = ww + (64 + c) * 9;
        const float* woc = wo + (64 + c) * 9;
        #pragma unroll
        for (int o = 0; o < 9; ++o)
            #pragma unroll
            for (int t = 0; t < 9; ++t) accW[o] = fmaf(wwc[o * 1152 + t], v9[t], accW[o]);
        #pragma unroll
        for (int o = 0; o < 18; ++o)
            #pragma unroll
            for (int t = 0; t < 9; ++t) accO[o] = fmaf(woc[o * 1152 + t], v9[t], accO[o]);
    }
    float wgt[9];
    float wsum = 0.0f;
    #pragma unroll
    for (int j = 0; j < 9; ++j) {
        const float inv = gw[j] * rsqrtf(vw[j] + EPS);
        const float x = fmaf(accW[j], inv, bw[j] - mw[j] * inv);
        const float s = 1.0f / (1.0f + expf(-x));
        wgt[j] = s; wsum += s;
    }
    const float wm = wsum * (1.0f / 9.0f);
    #pragma unroll
    for (int j = 0; j < 9; ++j) wgt[j] -= wm;
    float offv[18];
    #pragma unroll
    for (int j = 0; j < 18; ++j) {
        const float inv = go[j] * rsqrtf(vo[j] + EPS);
        offv[j] = fmaf(accO[j], inv, bo[j] - mo[j] * inv);
    }
    auto sampleD = [&](float xf, float yf) -> float {
        const bool vld = (xf >= 0.0f) & (xf <= 14.0f) & (yf >= 0.0f) & (yf <= 14.0f);
        const float xc = fminf(fmaxf(xf, 0.0f), 14.0f);
        const float yc = fminf(fmaxf(yf, 0.0f), 14.0f);
        const int xi = (int)xc, yi = (int)yc;
        const int yy = h + yi - 7, xx = w + xi - 7;
        const bool okimg = ((unsigned)yy < (unsigned)Hn) && ((unsigned)xx < (unsigned)Wn);
        return (vld && okimg) ? dimg[yy * Wn + xx] : 0.0f;
    };
    float res = 0.0f;
    #pragma unroll
    for (int i = 0; i < 3; ++i)
        #pragma unroll
        for (int j = 0; j < 3; ++j) {
            const int t = i * 3 + j;
            const float ox = offv[2 * t + 0], oy = offv[2 * t + 1];
            const float ix = (7.0f + (float)i + ox) * (14.0f / 15.0f);
            const float iy = (7.0f + (float)j + oy) * (14.0f / 15.0f);
            const float x0 = floorf(ix), y0 = floorf(iy);
            const float wx1 = ix - x0, wy1 = iy - y0;
            const float s = sampleD(x0, y0) * (1.0f - wx1) * (1.0f - wy1)
                          + sampleD(x0 + 1.0f, y0) * wx1 * (1.0f - wy1)
                          + sampleD(x0, y0 + 1.0f) * (1.0f - wx1) * wy1
                          + sampleD(x0 + 1.0f, y0 + 1.0f) * wx1 * wy1;
            res = fmaf(s, wgt[t], res);
        }
    out[n] = res + dimg[h * Wn + w];
}

extern "C" void kernel_launch(void* const* d_in, const int* in_sizes, int n_in,
                              void* d_out, int out_size, void* d_ws, size_t ws_size,
                              hipStream_t stream) {
    (void)in_sizes; (void)n_in; (void)out_size;
    const float* depth   = (const float*)d_in[0];
    const float* feature = (const float*)d_in[1];
    const float* w1 = (const float*)d_in[2];
    const float* g1 = (const float*)d_in[3];
    const float* b1 = (const float*)d_in[4];
    const float* m1 = (const float*)d_in[5];
    const float* v1 = (const float*)d_in[6];
    const float* ww = (const float*)d_in[7];
    const float* gw = (const float*)d_in[8];
    const float* bw = (const float*)d_in[9];
    const float* mw = (const float*)d_in[10];
    const float* vw = (const float*)d_in[11];
    const float* wo = (const float*)d_in[12];
    const float* go = (const float*)d_in[13];
    const float* bo = (const float*)d_in[14];
    const float* mo = (const float*)d_in[15];
    const float* vo = (const float*)d_in[16];
    float* out = (float*)d_out;

    if (ws_size >= WS_NEED) {
        unsigned short* Bmat = (unsigned short*)d_ws;
        unsigned short* catT = (unsigned short*)((char*)d_ws + CATT_OFF);
        hipLaunchKernelGGL(prep_cat, dim3((WP * 16 + 255) / 256, HP, Bn), dim3(256),
                           0, stream, depth, feature, w1, g1, b1, m1, v1, catT);
        hipLaunchKernelGGL(prep_B, dim3(5, 32), dim3(256), 0, stream, ww, wo, Bmat);
        hipLaunchKernelGGL(dkn_main, dim3(Wn / TN, Hn / TM, Bn), dim3(512), 0, stream,
                           catT, Bmat, depth, gw, bw, mw, vw, go, bo, mo, vo, out);
    } else {
        hipLaunchKernelGGL(dkn_fused_f32, dim3((Npix + 255) / 256), dim3(256), 0, stream,
                           depth, feature, w1, g1, b1, m1, v1,
                           ww, gw, bw, mw, vw, wo, go, bo, mo, vo, out);
    }
}